// Round 1
// baseline (82.970 us; speedup 1.0000x reference)
//
#include <hip/hip_runtime.h>

// EncoderSDP: masked path-max gather.
// B=16, L=512, P=32, D=256.
// out[b,l] = concat(max_p inputs[b, lpath[p]], max_p inputs[b, rpath[p]]), zeroed for l >= sent_lens[b].
//
// R3 design: the kernel is dependent-round-trip latency bound (the ~43us
// fillBufferAligned poison sweep is a fixed harness floor; kernel itself was
// ~39us). R2 serialized ~5.5 memory round trips per wave:
//   sent -> (len, idx chunk0) -> pbase[lm1] -> 2.5 gather chunks.
// R3 cuts this to ~2.5 trips:
//  - ALL scalar state (sent, len, all 32 indices) issued in ONE parallel trip
//    up front (2x s_load_dwordx16; always in-bounds since P=32 is allocated).
//  - Tail clamp uses idx[0] (valid since len>=1) instead of pbase[len-1],
//    killing the len->last dependent scalar load. max is idempotent and the
//    duplicate row loads are L1 hits (same wave-wide addresses).
//  - Gather chunk widened 8->16: E[ceil(len/16)] = 1.5 round trips (was 2.5).
//    16 pending dwordx4 = 64 data VGPRs; total ~75 stays under the 84-VGPR
//    cap for 6 waves/SIMD (__launch_bounds__(256,6)), so occupancy holds.
//  - Loads consumed in arrival order with two independent max chains so the
//    compiler emits minimal incremental vmcnt waits.

constexpr int BB = 16;
constexpr int LL = 512;
constexpr int PP = 32;
constexpr int D4 = 64;   // D/4 float4s per row
constexpr int CH = 16;   // gather chunk width (2 chunks max)

typedef float v4f __attribute__((ext_vector_type(4)));

__device__ __forceinline__ v4f v4max(v4f a, v4f b) {
    v4f r;
    r.x = fmaxf(a.x, b.x);
    r.y = fmaxf(a.y, b.y);
    r.z = fmaxf(a.z, b.z);
    r.w = fmaxf(a.w, b.w);
    return r;
}

__global__ __launch_bounds__(256, 6) void encoder_sdp_kernel(
    const v4f* __restrict__ inputs,      // [B, L, D4]
    const int* __restrict__ left_paths,  // [B, L, P]
    const int* __restrict__ right_paths, // [B, L, P]
    const int* __restrict__ left_lens,   // [B, L]
    const int* __restrict__ right_lens,  // [B, L]
    const int* __restrict__ sent_lens,   // [B]
    v4f*       __restrict__ out)         // [B, L, 2*D4]
{
    const int w    = threadIdx.x >> 6;   // wave 0..3 -> l offset
    const int lane = threadIdx.x & 63;
    const int b    = blockIdx.x & (BB - 1);   // XCD = blk%8 = b%8 -> 2 batches/XCD L2
    const int l    = ((blockIdx.x >> 4) << 2) + w;
    const int side = blockIdx.y;              // 0 = left, 1 = right (block-uniform)
    const int bl   = __builtin_amdgcn_readfirstlane(b * LL + l);

    const int* paths = side ? right_paths : left_paths;   // uniform select
    const int* lens  = side ? right_lens  : left_lens;
    const int* pbase = paths + (size_t)bl * PP;

    // ---- One parallel scalar round trip: sent + len + all 32 indices. ----
    const int sl  = sent_lens[b];                              // s_load
    const int len = __builtin_amdgcn_readfirstlane(lens[bl]);  // s_load, >= 1
    int idx[PP];
#pragma unroll
    for (int k = 0; k < PP; ++k) idx[k] = pbase[k];            // 2x s_load_dwordx16

    v4f* outp = out + (size_t)bl * (2 * D4) + side * D4 + lane;

    if (l >= sl) {
        v4f z = {0.f, 0.f, 0.f, 0.f};
        __builtin_nontemporal_store(z, outp);
        return;
    }

    const int lm1 = len - 1;
    const int i0  = idx[0];   // always a valid row: clamp target for the tail
    const v4f* base = inputs + (size_t)b * LL * D4 + lane;

    // ---- Chunk 0: 16 gathers in flight before any consume. ----
    v4f v[CH];
#pragma unroll
    for (int k = 0; k < CH; ++k) {
        const int j = (k <= lm1) ? idx[k] : i0;   // all-scalar select -> saddr form
        v[k] = base[(size_t)j * D4];
    }
    // Consume in arrival order, two independent chains.
    v4f a0 = v4max(v[0], v[1]);
    v4f a1 = v4max(v[2], v[3]);
#pragma unroll
    for (int k = 4; k < CH; k += 2) {
        a0 = v4max(a0, v[k]);
        a1 = v4max(a1, v[k + 1]);
    }
    v4f acc = v4max(a0, a1);

    // ---- Chunk 1 (uniform branch): only when len > 16. ----
    if (len > CH) {
        v4f u[CH];
#pragma unroll
        for (int k = 0; k < CH; ++k) {
            const int j = (CH + k <= lm1) ? idx[CH + k] : i0;
            u[k] = base[(size_t)j * D4];
        }
        v4f b0 = v4max(u[0], u[1]);
        v4f b1 = v4max(u[2], u[3]);
#pragma unroll
        for (int k = 4; k < CH; k += 2) {
            b0 = v4max(b0, u[k]);
            b1 = v4max(b1, u[k + 1]);
        }
        acc = v4max(acc, v4max(b0, b1));
    }

    __builtin_nontemporal_store(acc, outp);
}

extern "C" void kernel_launch(void* const* d_in, const int* in_sizes, int n_in,
                              void* d_out, int out_size, void* d_ws, size_t ws_size,
                              hipStream_t stream) {
    const v4f* inputs      = (const v4f*)d_in[0];
    const int* left_paths  = (const int*)d_in[1];
    const int* right_paths = (const int*)d_in[2];
    const int* left_lens   = (const int*)d_in[3];
    const int* right_lens  = (const int*)d_in[4];
    const int* sent_lens   = (const int*)d_in[5];
    v4f*       out         = (v4f*)d_out;

    // grid.x: 16 batches x 128 l-quads; grid.y: side
    encoder_sdp_kernel<<<dim3(BB * (LL / 4), 2), 256, 0, stream>>>(
        inputs, left_paths, right_paths, left_lens, right_lens, sent_lens, out);
}